// Round 4
// baseline (1857.024 us; speedup 1.0000x reference)
//
#include <hip/hip_runtime.h>
#include <hip/hip_bf16.h>

#define TCNT 8192   // B*S tokens
#define HDIM 1024
#define IDIM 2752
#define NEXP 8

#define BM 128      // down-GEMM m-tile
#define BN 64       // down-GEMM n-tile
#define BM2 256     // gu8 m-tile
#define BN2 128     // gu8 n-tile (I-cols; G+U both)

#define ABCAP 26624  // 8192 shared + 16384 routed + 8*256 pad

typedef short bf16x8 __attribute__((ext_vector_type(8)));
typedef float floatx4 __attribute__((ext_vector_type(4)));
typedef unsigned short ushortx8 __attribute__((ext_vector_type(8)));

__device__ __forceinline__ unsigned short f2bf(float f) {
    union { float f; unsigned u; } v; v.f = f;
    unsigned u = v.u;
    unsigned r = u + 0x7FFFu + ((u >> 16) & 1u);   // RNE
    return (unsigned short)(r >> 16);
}

// async global->LDS, 16B per lane; LDS dest = wave-uniform base + lane*16
__device__ __forceinline__ void async16(const unsigned short* g, unsigned short* l) {
    __builtin_amdgcn_global_load_lds(
        (const __attribute__((address_space(1))) unsigned int*)g,
        (__attribute__((address_space(3))) unsigned int*)l, 16, 0, 0);
}

#define BAR()  asm volatile("s_barrier" ::: "memory")

// ---------------- cast x fp32 -> bf16 (once) ----------------
__global__ void cast_x(const float* __restrict__ x, unsigned short* __restrict__ xb) {
    size_t i = (size_t)blockIdx.x * 256 + threadIdx.x;   // 8 elems per thread
    const float4* p = (const float4*)x + i * 2;
    float4 a = p[0], b = p[1];
    ushortx8 o;
    o[0] = f2bf(a.x); o[1] = f2bf(a.y); o[2] = f2bf(a.z); o[3] = f2bf(a.w);
    o[4] = f2bf(b.x); o[5] = f2bf(b.y); o[6] = f2bf(b.z); o[7] = f2bf(b.w);
    *(ushortx8*)(xb + i * 8) = o;
}

// ---------------- gate: softmax + top2, no global atomics ----------------
__global__ void gate_kernel(const float* __restrict__ x,
                            const float* __restrict__ gw,
                            int* __restrict__ topi,
                            float* __restrict__ topw) {
    int wave = threadIdx.x >> 6;
    int lane = threadIdx.x & 63;
    int t = blockIdx.x * 4 + wave;
    float acc[NEXP];
#pragma unroll
    for (int e = 0; e < NEXP; e++) acc[e] = 0.f;
    const float* xp = x + (size_t)t * HDIM;
#pragma unroll
    for (int it = 0; it < HDIM / 64; it++) {
        float xv = xp[lane + 64 * it];
#pragma unroll
        for (int e = 0; e < NEXP; e++)
            acc[e] += xv * gw[e * HDIM + lane + 64 * it];
    }
#pragma unroll
    for (int e = 0; e < NEXP; e++) {
#pragma unroll
        for (int off = 32; off > 0; off >>= 1)
            acc[e] += __shfl_xor(acc[e], off);
    }
    if (lane == 0) {
        float m = acc[0];
#pragma unroll
        for (int e = 1; e < NEXP; e++) m = fmaxf(m, acc[e]);
        float p[NEXP], Z = 0.f;
#pragma unroll
        for (int e = 0; e < NEXP; e++) { p[e] = expf(acc[e] - m); Z += p[e]; }
        int i0 = 0;
#pragma unroll
        for (int e = 1; e < NEXP; e++) if (acc[e] > acc[i0]) i0 = e;
        int i1 = (i0 == 0) ? 1 : 0;
#pragma unroll
        for (int e = 0; e < NEXP; e++) {
            if (e == i0 || e == i1) continue;
            if (acc[e] > acc[i1]) i1 = e;
        }
        float p0 = p[i0] / Z, p1 = p[i1] / Z;
        float s = p0 + p1 + 1e-20f;
        topi[t * 2 + 0] = i0;  topw[t * 2 + 0] = p0 / s;
        topi[t * 2 + 1] = i1;  topw[t * 2 + 1] = p1 / s;
    }
}

// ---------------- compaction: one block per expert, LDS-atomic positions ----------------
__global__ void compact_k(const int* __restrict__ topi, const float* __restrict__ topw,
                          int* __restrict__ pcnt,
                          int* __restrict__ idxb, float* __restrict__ wgtb) {
    int e = blockIdx.x;
    __shared__ int base;
    if (threadIdx.x == 0) base = 0;
    __syncthreads();
    for (int i = threadIdx.x; i < 2 * TCNT; i += 256) {
        if (topi[i] == e) {
            int p = atomicAdd(&base, 1);
            idxb[e * TCNT + p] = i >> 1;
            wgtb[e * TCNT + p] = topw[i];
        }
    }
    __syncthreads();
    int c = base;
    int pc = (c + BM2 - 1) & ~(BM2 - 1);     // pad to 256 for gu8 tile
    for (int i = c + threadIdx.x; i < pc; i += 256) {
        idxb[e * TCNT + i] = 0;
        wgtb[e * TCNT + i] = 0.f;
    }
    if (threadIdx.x == 0) pcnt[e] = pc;
}

// ---------------- Ab row offsets ----------------
__global__ void offsets_k(const int* __restrict__ pcnt, int* __restrict__ abrow, int fused) {
    if (threadIdx.x == 0) {
        int off = TCNT;
        for (int e = 0; e < NEXP; e++) {
            abrow[e] = fused ? off : 0;
            off += pcnt[e];
        }
        abrow[8] = 0;
    }
}

// ---------------- transpose+cast G/U: [H,I] fp32 -> [I,H] bf16 ----------------
__global__ void trans_gu_all(const float* __restrict__ wg, const float* __restrict__ sg,
                             const float* __restrict__ wu, const float* __restrict__ su,
                             unsigned short* __restrict__ outg, unsigned short* __restrict__ outu,
                             int zbase, size_t ostride) {
    const size_t HI = (size_t)HDIM * IDIM;
    int z = zbase + blockIdx.z;
    int e = z >> 1, which = z & 1;
    const float* in = which ? (e < 8 ? wu + (size_t)e * HI : su)
                            : (e < 8 ? wg + (size_t)e * HI : sg);
    unsigned short* out = (which ? outu : outg) + (size_t)e * ostride;
    const int R = HDIM, C = IDIM;
    __shared__ float tile[32][33];
    int r0 = blockIdx.y * 32, c0 = blockIdx.x * 32;
    int ty = threadIdx.x >> 3, tx = (threadIdx.x & 7) * 4;
    float4 v = *(const float4*)&in[(size_t)(r0 + ty) * C + c0 + tx];
    tile[ty][tx + 0] = v.x; tile[ty][tx + 1] = v.y;
    tile[ty][tx + 2] = v.z; tile[ty][tx + 3] = v.w;
    __syncthreads();
    int cy = ty, rx = tx;
    ushort4 o;
    o.x = f2bf(tile[rx + 0][cy]); o.y = f2bf(tile[rx + 1][cy]);
    o.z = f2bf(tile[rx + 2][cy]); o.w = f2bf(tile[rx + 3][cy]);
    *(ushort4*)&out[(size_t)(c0 + cy) * R + r0 + rx] = o;
}

// ---------------- transpose+cast D: [I,H] fp32 -> [H,I] bf16 ----------------
__global__ void trans_d_all(const float* __restrict__ wd, const float* __restrict__ sd,
                            unsigned short* __restrict__ outd, int zbase, size_t ostride) {
    const size_t HI = (size_t)HDIM * IDIM;
    int e = zbase + blockIdx.z;
    const float* in = (e < 8) ? wd + (size_t)e * HI : sd;
    unsigned short* out = outd + (size_t)e * ostride;
    const int R = IDIM, C = HDIM;
    __shared__ float tile[32][33];
    int r0 = blockIdx.y * 32, c0 = blockIdx.x * 32;
    int ty = threadIdx.x >> 3, tx = (threadIdx.x & 7) * 4;
    float4 v = *(const float4*)&in[(size_t)(r0 + ty) * C + c0 + tx];
    tile[ty][tx + 0] = v.x; tile[ty][tx + 1] = v.y;
    tile[ty][tx + 2] = v.z; tile[ty][tx + 3] = v.w;
    __syncthreads();
    int cy = ty, rx = tx;
    ushort4 o;
    o.x = f2bf(tile[rx + 0][cy]); o.y = f2bf(tile[rx + 1][cy]);
    o.z = f2bf(tile[rx + 2][cy]); o.w = f2bf(tile[rx + 3][cy]);
    *(ushort4*)&out[(size_t)(c0 + cy) * R + r0 + rx] = o;
}

// ---------------- 8-phase fused G/U GEMM + SwiGLU ----------------
// 512 thr (8 waves 4m x 2n); tile 256 tokens x 128 I-cols x {G,U}; BK=64;
// double-buffered LDS; counted vmcnt (4 @P1, 6 @P3); raw s_barrier; setprio.
__global__ void __launch_bounds__(512, 2)
gemm_gu8(const unsigned short* __restrict__ xb,
         const unsigned short* __restrict__ Wg,
         const unsigned short* __restrict__ Wu,
         size_t wstride,
         const int* __restrict__ idxb,
         const int* __restrict__ pcnt,
         const int* __restrict__ abrow,
         unsigned short* __restrict__ Ab,
         int zbase) {
    const int e = zbase + blockIdx.z;
    const int cnt = (e == 8) ? TCNT : pcnt[e];
    const int m0 = blockIdx.x * BM2;
    if (m0 >= cnt) return;
    const int n0 = blockIdx.y * BN2;
    const unsigned short* GT = Wg + (size_t)e * wstride;
    const unsigned short* UT = Wu + (size_t)e * wstride;
    const int* idx = (e == 8) ? nullptr : idxb + e * TCNT;
    const int ab0 = abrow[e];

    __shared__ unsigned short Xs[2][BM2][64];
    __shared__ unsigned short Gs[2][BN2][64];
    __shared__ unsigned short Us[2][BN2][64];
    __shared__ int toks[BM2];

    const int tid = threadIdx.x;
    const int wave = tid >> 6, lane = tid & 63;
    const int quad = lane >> 4, l16 = lane & 15;
    const int sl = l16 & 7;
    const int wm = wave >> 1, wn = wave & 1;   // 4m x 2n waves; 64 rows x 64 cols (G+U)
    const int wn64 = wn * 64;
    const int w16 = wave * 16;
    const int rr = lane >> 3, cc = lane & 7;
    const int sw = (cc ^ rr) << 3;             // inverse-swizzled source slot (elems)

    if (tid < BM2) toks[tid] = idx ? idx[m0 + tid] : (m0 + tid);
    __syncthreads();

    // per-lane staging source pointers (loop-invariant)
    const unsigned short* xs0 = xb + (size_t)toks[w16 + rr] * HDIM + sw;
    const unsigned short* xs1 = xb + (size_t)toks[w16 + 8 + rr] * HDIM + sw;
    const unsigned short* xs2 = xb + (size_t)toks[128 + w16 + rr] * HDIM + sw;
    const unsigned short* xs3 = xb + (size_t)toks[128 + w16 + 8 + rr] * HDIM + sw;
    const int gr0 = min(n0 + w16 + rr, IDIM - 1);        // clamp for IDIM tail
    const int gr1 = min(n0 + w16 + 8 + rr, IDIM - 1);
    const unsigned short* gs0 = GT + (size_t)gr0 * HDIM + sw;
    const unsigned short* gs1 = GT + (size_t)gr1 * HDIM + sw;
    const unsigned short* us0 = UT + (size_t)gr0 * HDIM + sw;
    const unsigned short* us1 = UT + (size_t)gr1 * HDIM + sw;

#define ST_C0(nb, kk) { async16(xs0 + (kk), &Xs[nb][w16][0]);       async16(xs1 + (kk), &Xs[nb][w16 + 8][0]); }
#define ST_C1(nb, kk) { async16(xs2 + (kk), &Xs[nb][128 + w16][0]); async16(xs3 + (kk), &Xs[nb][128 + w16 + 8][0]); }
#define ST_C2(nb, kk) { async16(gs0 + (kk), &Gs[nb][w16][0]);       async16(gs1 + (kk), &Gs[nb][w16 + 8][0]); }
#define ST_C3(nb, kk) { async16(us0 + (kk), &Us[nb][w16][0]);       async16(us1 + (kk), &Us[nb][w16 + 8][0]); }

    floatx4 accG[4][4], accU[4][4];
#pragma unroll
    for (int mi = 0; mi < 4; mi++)
#pragma unroll
        for (int nj = 0; nj < 4; nj++) {
            accG[mi][nj] = (floatx4){0.f, 0.f, 0.f, 0.f};
            accU[mi][nj] = (floatx4){0.f, 0.f, 0.f, 0.f};
        }

    // prologue: stage all 4 chunks of tile 0 into buf 0
    ST_C0(0, 0); ST_C1(0, 0); ST_C2(0, 0); ST_C3(0, 0);

    const int NT = HDIM / 64;   // 16 K-tiles

#define PHASE_BODY(SRC, NJ0, ACC, b)                                                 \
    {                                                                                \
        bf16x8 bb[2][2];                                                             \
        _Pragma("unroll") for (int j = 0; j < 2; j++)                                \
            _Pragma("unroll") for (int h = 0; h < 2; h++) {                          \
                int row = wn64 + (NJ0 + j) * 16 + l16;                               \
                bb[j][h] = *(const bf16x8*)&SRC[b][row][(((h << 2) + quad) ^ sl) << 3]; \
            }                                                                        \
        __builtin_amdgcn_s_setprio(1);                                               \
        _Pragma("unroll") for (int j = 0; j < 2; j++)                                \
            _Pragma("unroll") for (int mi = 0; mi < 4; mi++)                         \
                _Pragma("unroll") for (int h = 0; h < 2; h++)                        \
                    ACC[mi][NJ0 + j] = __builtin_amdgcn_mfma_f32_16x16x32_bf16(      \
                        af[mi][h], bb[j][h], ACC[mi][NJ0 + j], 0, 0, 0);             \
        __builtin_amdgcn_s_setprio(0);                                               \
    }

#pragma unroll 1
    for (int t = 0; t < NT; ++t) {
        const int b = t & 1, nb = b ^ 1;
        const int kk = (((t + 1) & (NT - 1)) << 6);   // next-tile K offset (wraps; last-iter loads unused)

        bf16x8 af[4][2];
        // ---- P1: G nj 0,1 ---- (needs C0,C1,C2 of t; leaves C3(t)+C0(t+1) = 4 in flight)
        ST_C0(nb, kk);
        asm volatile("s_waitcnt vmcnt(4)" ::: "memory");
        BAR();
#pragma unroll
        for (int mi = 0; mi < 4; mi++)
#pragma unroll
            for (int h = 0; h < 2; h++) {
                int row = wm * 64 + mi * 16 + l16;
                af[mi][h] = *(const bf16x8*)&Xs[b][row][(((h << 2) + quad) ^ sl) << 3];
            }
        PHASE_BODY(Gs, 0, accG, b);
        BAR();
        // ---- P2: G nj 2,3 ----
        ST_C1(nb, kk);
        BAR();
        PHASE_BODY(Gs, 2, accG, b);
        BAR();
        // ---- P3: U nj 0,1 ---- (needs C3 of t; leaves 3 chunks of t+1 = 6 in flight)
        ST_C2(nb, kk);
        asm volatile("s_waitcnt vmcnt(6)" ::: "memory");
        BAR();
        PHASE_BODY(Us, 0, accU, b);
        BAR();
        // ---- P4: U nj 2,3 ----
        ST_C3(nb, kk);
        BAR();
        PHASE_BODY(Us, 2, accU, b);
        BAR();
    }

    // epilogue: SwiGLU + store
#pragma unroll
    for (int mi = 0; mi < 4; mi++)
#pragma unroll
        for (int nj = 0; nj < 4; nj++)
#pragma unroll
            for (int r = 0; r < 4; r++) {
                int m = ab0 + m0 + wm * 64 + mi * 16 + quad * 4 + r;
                int n = n0 + wn64 + nj * 16 + l16;
                if (n < IDIM) {
                    float g = accG[mi][nj][r], u = accU[mi][nj][r];
                    float a = g / (1.f + expf(-g)) * u;
                    Ab[(size_t)m * IDIM + n] = f2bf(a);
                }
            }
#undef ST_C0
#undef ST_C1
#undef ST_C2
#undef ST_C3
#undef PHASE_BODY
}

// ---------------- down GEMM (round-2-verified structure): scatter-add / store --------
__global__ void gemm_down_all(const unsigned short* __restrict__ Ab,
                              const unsigned short* __restrict__ Wd,
                              size_t wstride,
                              const int* __restrict__ idxb,
                              const float* __restrict__ wgtb,
                              const int* __restrict__ pcnt,
                              const int* __restrict__ abrow,
                              float* __restrict__ Y,
                              int zbase) {
    const int e = zbase + blockIdx.z;
    const int cnt = (e == 8) ? TCNT : pcnt[e];
    const int m0 = blockIdx.x * BM;
    if (m0 >= cnt) return;
    const int n0 = blockIdx.y * BN;
    const unsigned short* DT = Wd + (size_t)e * wstride;
    const int* idx = (e == 8) ? nullptr : idxb + e * TCNT;
    const float* wgt = (e == 8) ? nullptr : wgtb + e * TCNT;
    const int ab0 = abrow[e];

    __shared__ unsigned short As[BM][64];
    __shared__ unsigned short Ws[BN][64];
    __shared__ int toks[BM];
    __shared__ float tw[BM];

    const int tid = threadIdx.x;
    const int wave = tid >> 6, lane = tid & 63;
    const int quad = lane >> 4, l16 = lane & 15;
    const int wm = wave >> 1, wn = wave & 1;

    if (tid < BM) {
        toks[tid] = idx ? idx[m0 + tid] : (m0 + tid);
        tw[tid] = wgt ? wgt[m0 + tid] : 1.0f;
    }
    __syncthreads();

    floatx4 acc[4][2];
#pragma unroll
    for (int mi = 0; mi < 4; mi++)
#pragma unroll
        for (int nj = 0; nj < 2; nj++) acc[mi][nj] = (floatx4){0.f, 0.f, 0.f, 0.f};

    const int rr = lane >> 3, cc = lane & 7;
    const int sw = (cc ^ rr) * 8;
    for (int kb = 0; kb < IDIM; kb += 64) {
#pragma unroll
        for (int s = 0; s < 4; s++) {
            int bs = wave * 32 + s * 8;
            async16(Ab + (size_t)(ab0 + m0 + bs + rr) * IDIM + kb + sw, &As[bs][0]);
        }
        async16(DT + (size_t)(n0 + wave * 16 + rr) * IDIM + kb + sw, &Ws[wave * 16][0]);
        async16(DT + (size_t)(n0 + wave * 16 + 8 + rr) * IDIM + kb + sw, &Ws[wave * 16 + 8][0]);
        __syncthreads();

#pragma unroll
        for (int h = 0; h < 2; h++) {
            bf16x8 af[4], bw[2];
#pragma unroll
            for (int mi = 0; mi < 4; mi++) {
                int row = wm * 64 + mi * 16 + l16;
                af[mi] = *(const bf16x8*)&As[row][(((h << 2) + quad) ^ (row & 7)) * 8];
            }
#pragma unroll
            for (int nj = 0; nj < 2; nj++) {
                int row = wn * 32 + nj * 16 + l16;
                bw[nj] = *(const bf16x8*)&Ws[row][(((h << 2) + quad) ^ (row & 7)) * 8];
            }
#pragma unroll
            for (int mi = 0; mi < 4; mi++)
#pragma unroll
                for (int nj = 0; nj < 2; nj++)
                    acc[mi][nj] = __builtin_amdgcn_mfma_f32_16x16x32_bf16(af[mi], bw[nj], acc[mi][nj], 0, 0, 0);
        }
        __syncthreads();
    }

    if (e != 8) {
#pragma unroll
        for (int mi = 0; mi < 4; mi++)
#pragma unroll
            for (int r = 0; r < 4; r++) {
                int lm = wm * 64 + mi * 16 + quad * 4 + r;
                int t = toks[lm];
                float w = tw[lm];
#pragma unroll
                for (int nj = 0; nj < 2; nj++) {
                    int n = n0 + wn * 32 + nj * 16 + l16;
                    atomicAdd(&Y[(size_t)t * HDIM + n], w * acc[mi][nj][r]);
                }
            }
    } else {
#pragma unroll
        for (int mi = 0; mi < 4; mi++)
#pragma unroll
            for (int r = 0; r < 4; r++) {
                int m = m0 + wm * 64 + mi * 16 + quad * 4 + r;
#pragma unroll
                for (int nj = 0; nj < 2; nj++) {
                    int n = n0 + wn * 32 + nj * 16 + l16;
                    Y[(size_t)m * HDIM + n] = acc[mi][nj][r];
                }
            }
    }
}

extern "C" void kernel_launch(void* const* d_in, const int* in_sizes, int n_in,
                              void* d_out, int out_size, void* d_ws, size_t ws_size,
                              hipStream_t stream) {
    const float* x      = (const float*)d_in[0];
    const float* gate_w = (const float*)d_in[1];
    const float* wg     = (const float*)d_in[2];
    const float* wu     = (const float*)d_in[3];
    const float* wd     = (const float*)d_in[4];
    const float* sg     = (const float*)d_in[5];
    const float* su     = (const float*)d_in[6];
    const float* sd     = (const float*)d_in[7];
    float* y = (float*)d_out;

    const size_t HI   = (size_t)HDIM * IDIM;
    const size_t XB_B = (size_t)TCNT * HDIM * 2;
    const size_t LISTS_B = (size_t)NEXP * TCNT * 8 + (size_t)4 * TCNT * 4 + 256;
    const size_t full_need = XB_B + 18 * HI * 2 + (size_t)ABCAP * IDIM * 2 + LISTS_B;

    const int GY = (IDIM + BN2 - 1) / BN2;   // 22 (tail-guarded)

    if (ws_size >= full_need) {
        // -------- fused mode --------
        unsigned short* xb  = (unsigned short*)d_ws;
        unsigned short* WgA = xb + (size_t)TCNT * HDIM;   // [9][I][H]
        unsigned short* WuA = WgA + 9 * HI;               // [9][I][H]
        unsigned short* WdA = WgA;                        // alias: trans_d after gu8
        unsigned short* Ab  = WuA + 9 * HI;               // [ABCAP][I]
        int*   idxb  = (int*)(Ab + (size_t)ABCAP * IDIM);
        float* wgtb  = (float*)(idxb + NEXP * TCNT);
        int*   topi  = (int*)(wgtb + NEXP * TCNT);
        float* topw  = (float*)(topi + 2 * TCNT);
        int*   pcnt  = (int*)(topw + 2 * TCNT);
        int*   abrow = pcnt + 16;

        cast_x<<<TCNT * HDIM / (256 * 8), 256, 0, stream>>>(x, xb);
        gate_kernel<<<TCNT / 4, 256, 0, stream>>>(x, gate_w, topi, topw);
        compact_k<<<NEXP, 256, 0, stream>>>(topi, topw, pcnt, idxb, wgtb);
        offsets_k<<<1, 64, 0, stream>>>(pcnt, abrow, 1);

        trans_gu_all<<<dim3(IDIM / 32, HDIM / 32, 18), 256, 0, stream>>>(
            wg, sg, wu, su, WgA, WuA, 0, HI);
        gemm_gu8<<<dim3(TCNT / BM2, GY, 9), 512, 0, stream>>>(
            xb, WgA, WuA, HI, idxb, pcnt, abrow, Ab, 0);
        trans_d_all<<<dim3(HDIM / 32, IDIM / 32, 9), 256, 0, stream>>>(wd, sd, WdA, 0, HI);
        gemm_down_all<<<dim3(TCNT / BM, HDIM / BN, 1), 256, 0, stream>>>(
            Ab, WdA, HI, idxb, wgtb, pcnt, abrow, y, 8);
        gemm_down_all<<<dim3(TCNT / BM, HDIM / BN, 8), 256, 0, stream>>>(
            Ab, WdA, HI, idxb, wgtb, pcnt, abrow, y, 0);
    } else {
        // -------- fallback: sequential per-expert --------
        unsigned short* WgT = (unsigned short*)d_ws;
        unsigned short* WuT = WgT + HI;
        unsigned short* Ab  = WuT + HI;                   // [T][I]
        int*   idxb  = (int*)(Ab + (size_t)TCNT * IDIM);
        float* wgtb  = (float*)(idxb + NEXP * TCNT);
        int*   topi  = (int*)(wgtb + NEXP * TCNT);
        float* topw  = (float*)(topi + 2 * TCNT);
        int*   pcnt  = (int*)(topw + 2 * TCNT);
        int*   abrow = pcnt + 16;
        unsigned short* xb = (unsigned short*)(abrow + 16);
        unsigned short* WdT = WgT;

        cast_x<<<TCNT * HDIM / (256 * 8), 256, 0, stream>>>(x, xb);
        gate_kernel<<<TCNT / 4, 256, 0, stream>>>(x, gate_w, topi, topw);
        compact_k<<<NEXP, 256, 0, stream>>>(topi, topw, pcnt, idxb, wgtb);
        offsets_k<<<1, 64, 0, stream>>>(pcnt, abrow, 0);

        trans_gu_all<<<dim3(IDIM / 32, HDIM / 32, 2), 256, 0, stream>>>(
            wg, sg, wu, su, WgT, WuT, 16, 0);
        gemm_gu8<<<dim3(TCNT / BM2, GY, 1), 512, 0, stream>>>(
            xb, WgT, WuT, 0, idxb, pcnt, abrow, Ab, 8);
        trans_d_all<<<dim3(HDIM / 32, IDIM / 32, 1), 256, 0, stream>>>(wd, sd, WdT, 8, 0);
        gemm_down_all<<<dim3(TCNT / BM, HDIM / BN, 1), 256, 0, stream>>>(
            Ab, WdT, 0, idxb, wgtb, pcnt, abrow, y, 8);

        for (int e = 0; e < NEXP; e++) {
            trans_gu_all<<<dim3(IDIM / 32, HDIM / 32, 2), 256, 0, stream>>>(
                wg, sg, wu, su, WgT, WuT, 2 * e, 0);
            gemm_gu8<<<dim3(TCNT / BM2, GY, 1), 512, 0, stream>>>(
                xb, WgT, WuT, 0, idxb, pcnt, abrow, Ab, e);
            trans_d_all<<<dim3(HDIM / 32, IDIM / 32, 1), 256, 0, stream>>>(wd, sd, WdT, e, 0);
            gemm_down_all<<<dim3(TCNT / BM, HDIM / BN, 1), 256, 0, stream>>>(
                Ab, WdT, 0, idxb, wgtb, pcnt, abrow, y, e);
        }
    }
}

// Round 5
// 1387.862 us; speedup vs baseline: 1.3380x; 1.3380x over previous
//
#include <hip/hip_runtime.h>
#include <hip/hip_bf16.h>

#define TCNT 8192   // B*S tokens
#define HDIM 1024
#define IDIM 2752
#define NEXP 8

#define BM 128
#define BN 64
// BK = 64 (128B LDS rows, XOR-swizzled), double-buffered

#define ABCAP 25600  // 8192 shared + 16384 routed + 8*128 pad

typedef short bf16x8 __attribute__((ext_vector_type(8)));
typedef float floatx4 __attribute__((ext_vector_type(4)));
typedef unsigned short ushortx8 __attribute__((ext_vector_type(8)));

__device__ __forceinline__ unsigned short f2bf(float f) {
    union { float f; unsigned u; } v; v.f = f;
    unsigned u = v.u;
    unsigned r = u + 0x7FFFu + ((u >> 16) & 1u);   // RNE
    return (unsigned short)(r >> 16);
}

// async global->LDS, 16B per lane; LDS dest = wave-uniform base + lane*16
__device__ __forceinline__ void async16(const unsigned short* g, unsigned short* l) {
    __builtin_amdgcn_global_load_lds(
        (const __attribute__((address_space(1))) unsigned int*)g,
        (__attribute__((address_space(3))) unsigned int*)l, 16, 0, 0);
}

// ---------------- zero Y ----------------
__global__ void zero_y(float* __restrict__ y) {
    size_t i = ((size_t)blockIdx.x * 256 + threadIdx.x) * 4;
    *(float4*)&y[i] = make_float4(0.f, 0.f, 0.f, 0.f);
}

// ---------------- cast x fp32 -> bf16 (once) ----------------
__global__ void cast_x(const float* __restrict__ x, unsigned short* __restrict__ xb) {
    size_t i = (size_t)blockIdx.x * 256 + threadIdx.x;   // 8 elems per thread
    const float4* p = (const float4*)x + i * 2;
    float4 a = p[0], b = p[1];
    ushortx8 o;
    o[0] = f2bf(a.x); o[1] = f2bf(a.y); o[2] = f2bf(a.z); o[3] = f2bf(a.w);
    o[4] = f2bf(b.x); o[5] = f2bf(b.y); o[6] = f2bf(b.z); o[7] = f2bf(b.w);
    *(ushortx8*)(xb + i * 8) = o;
}

// ---------------- gate: softmax + top2, no global atomics ----------------
__global__ void gate_kernel(const float* __restrict__ x,
                            const float* __restrict__ gw,
                            int* __restrict__ topi,
                            float* __restrict__ topw) {
    int wave = threadIdx.x >> 6;
    int lane = threadIdx.x & 63;
    int t = blockIdx.x * 4 + wave;
    float acc[NEXP];
#pragma unroll
    for (int e = 0; e < NEXP; e++) acc[e] = 0.f;
    const float* xp = x + (size_t)t * HDIM;
#pragma unroll
    for (int it = 0; it < HDIM / 64; it++) {
        float xv = xp[lane + 64 * it];
#pragma unroll
        for (int e = 0; e < NEXP; e++)
            acc[e] += xv * gw[e * HDIM + lane + 64 * it];
    }
#pragma unroll
    for (int e = 0; e < NEXP; e++) {
#pragma unroll
        for (int off = 32; off > 0; off >>= 1)
            acc[e] += __shfl_xor(acc[e], off);
    }
    if (lane == 0) {
        float m = acc[0];
#pragma unroll
        for (int e = 1; e < NEXP; e++) m = fmaxf(m, acc[e]);
        float p[NEXP], Z = 0.f;
#pragma unroll
        for (int e = 0; e < NEXP; e++) { p[e] = expf(acc[e] - m); Z += p[e]; }
        int i0 = 0;
#pragma unroll
        for (int e = 1; e < NEXP; e++) if (acc[e] > acc[i0]) i0 = e;
        int i1 = (i0 == 0) ? 1 : 0;
#pragma unroll
        for (int e = 0; e < NEXP; e++) {
            if (e == i0 || e == i1) continue;
            if (acc[e] > acc[i1]) i1 = e;
        }
        float p0 = p[i0] / Z, p1 = p[i1] / Z;
        float s = p0 + p1 + 1e-20f;
        topi[t * 2 + 0] = i0;  topw[t * 2 + 0] = p0 / s;
        topi[t * 2 + 1] = i1;  topw[t * 2 + 1] = p1 / s;
    }
}

// ---------------- compaction: one block per expert, LDS-atomic positions ----------------
__global__ void compact_k(const int* __restrict__ topi, const float* __restrict__ topw,
                          int* __restrict__ pcnt,
                          int* __restrict__ idxb, float* __restrict__ wgtb) {
    int e = blockIdx.x;
    __shared__ int base;
    if (threadIdx.x == 0) base = 0;
    __syncthreads();
    for (int i = threadIdx.x; i < 2 * TCNT; i += 256) {
        if (topi[i] == e) {
            int p = atomicAdd(&base, 1);
            idxb[e * TCNT + p] = i >> 1;
            wgtb[e * TCNT + p] = topw[i];
        }
    }
    __syncthreads();
    int c = base;
    int pc = (c + BM - 1) & ~(BM - 1);
    for (int i = c + threadIdx.x; i < pc; i += 256) {
        idxb[e * TCNT + i] = 0;
        wgtb[e * TCNT + i] = 0.f;
    }
    if (threadIdx.x == 0) pcnt[e] = pc;
}

// ---------------- Ab row offsets ----------------
__global__ void offsets_k(const int* __restrict__ pcnt, int* __restrict__ abrow, int fused) {
    if (threadIdx.x == 0) {
        int off = TCNT;
        for (int e = 0; e < NEXP; e++) {
            abrow[e] = fused ? off : 0;
            off += pcnt[e];
        }
        abrow[8] = 0;
    }
}

// ---------------- transpose+cast G/U: [H,I] fp32 -> [I,H] bf16 ----------------
__global__ void trans_gu_all(const float* __restrict__ wg, const float* __restrict__ sg,
                             const float* __restrict__ wu, const float* __restrict__ su,
                             unsigned short* __restrict__ outg, unsigned short* __restrict__ outu,
                             int zbase, size_t ostride) {
    const size_t HI = (size_t)HDIM * IDIM;
    int z = zbase + blockIdx.z;
    int e = z >> 1, which = z & 1;
    const float* in = which ? (e < 8 ? wu + (size_t)e * HI : su)
                            : (e < 8 ? wg + (size_t)e * HI : sg);
    unsigned short* out = (which ? outu : outg) + (size_t)e * ostride;
    const int R = HDIM, C = IDIM;
    __shared__ float tile[32][33];
    int r0 = blockIdx.y * 32, c0 = blockIdx.x * 32;
    int ty = threadIdx.x >> 3, tx = (threadIdx.x & 7) * 4;
    float4 v = *(const float4*)&in[(size_t)(r0 + ty) * C + c0 + tx];
    tile[ty][tx + 0] = v.x; tile[ty][tx + 1] = v.y;
    tile[ty][tx + 2] = v.z; tile[ty][tx + 3] = v.w;
    __syncthreads();
    int cy = ty, rx = tx;
    ushort4 o;
    o.x = f2bf(tile[rx + 0][cy]); o.y = f2bf(tile[rx + 1][cy]);
    o.z = f2bf(tile[rx + 2][cy]); o.w = f2bf(tile[rx + 3][cy]);
    *(ushort4*)&out[(size_t)(c0 + cy) * R + r0 + rx] = o;
}

// ---------------- transpose+cast D: [I,H] fp32 -> [H,I] bf16 ----------------
__global__ void trans_d_all(const float* __restrict__ wd, const float* __restrict__ sd,
                            unsigned short* __restrict__ outd, int zbase, size_t ostride) {
    const size_t HI = (size_t)HDIM * IDIM;
    int e = zbase + blockIdx.z;
    const float* in = (e < 8) ? wd + (size_t)e * HI : sd;
    unsigned short* out = outd + (size_t)e * ostride;
    const int R = IDIM, C = HDIM;
    __shared__ float tile[32][33];
    int r0 = blockIdx.y * 32, c0 = blockIdx.x * 32;
    int ty = threadIdx.x >> 3, tx = (threadIdx.x & 7) * 4;
    float4 v = *(const float4*)&in[(size_t)(r0 + ty) * C + c0 + tx];
    tile[ty][tx + 0] = v.x; tile[ty][tx + 1] = v.y;
    tile[ty][tx + 2] = v.z; tile[ty][tx + 3] = v.w;
    __syncthreads();
    int cy = ty, rx = tx;
    ushort4 o;
    o.x = f2bf(tile[rx + 0][cy]); o.y = f2bf(tile[rx + 1][cy]);
    o.z = f2bf(tile[rx + 2][cy]); o.w = f2bf(tile[rx + 3][cy]);
    *(ushort4*)&out[(size_t)(c0 + cy) * R + r0 + rx] = o;
}

// ---------------- double-buffered 2-phase fused G/U GEMM + SwiGLU ----------------
// T3 minimum recipe: STAGE(next) before compute(cur); one vmcnt(0)+s_barrier per tile.
__global__ void __launch_bounds__(256, 2)
gemm_gu_db(const unsigned short* __restrict__ xb,
           const unsigned short* __restrict__ Wg,
           const unsigned short* __restrict__ Wu,
           size_t wstride,
           const int* __restrict__ idxb,
           const int* __restrict__ pcnt,
           const int* __restrict__ abrow,
           unsigned short* __restrict__ Ab,
           int zbase) {
    const int e = zbase + blockIdx.z;
    const int cnt = (e == 8) ? TCNT : pcnt[e];
    const int m0 = blockIdx.x * BM;
    if (m0 >= cnt) return;
    const int n0 = blockIdx.y * BN;
    const unsigned short* GT = Wg + (size_t)e * wstride;
    const unsigned short* UT = Wu + (size_t)e * wstride;
    const int* idx = (e == 8) ? nullptr : idxb + e * TCNT;
    const int ab0 = abrow[e];

    __shared__ unsigned short Xs[2][BM][64];   // 32 KB
    __shared__ unsigned short Gs[2][BN][64];   // 16 KB
    __shared__ unsigned short Us[2][BN][64];   // 16 KB
    __shared__ int toks[BM];

    const int tid = threadIdx.x;
    const int wave = tid >> 6, lane = tid & 63;
    const int quad = lane >> 4, l16 = lane & 15;
    const int sl = l16 & 7;
    const int wm = wave >> 1, wn = wave & 1;   // wave tile: 64 m x 32 n
    const int w16 = wave * 16, w32 = wave * 32;
    const int rr = lane >> 3, cc = lane & 7;
    const int sw = (cc ^ rr) << 3;             // inverse-swizzled source slot (elems)

    if (tid < BM) toks[tid] = idx ? idx[m0 + tid] : (m0 + tid);
    __syncthreads();

    const unsigned short* xp0 = xb + (size_t)toks[w32 + rr] * HDIM + sw;
    const unsigned short* xp1 = xb + (size_t)toks[w32 + 8 + rr] * HDIM + sw;
    const unsigned short* xp2 = xb + (size_t)toks[w32 + 16 + rr] * HDIM + sw;
    const unsigned short* xp3 = xb + (size_t)toks[w32 + 24 + rr] * HDIM + sw;
    const unsigned short* gp0 = GT + (size_t)(n0 + w16 + rr) * HDIM + sw;
    const unsigned short* gp1 = GT + (size_t)(n0 + w16 + 8 + rr) * HDIM + sw;
    const unsigned short* up0 = UT + (size_t)(n0 + w16 + rr) * HDIM + sw;
    const unsigned short* up1 = UT + (size_t)(n0 + w16 + 8 + rr) * HDIM + sw;

#define STAGE(nb, kk) {                                                        \
    async16(gp0 + (kk), &Gs[nb][w16][0]);  async16(gp1 + (kk), &Gs[nb][w16 + 8][0]); \
    async16(up0 + (kk), &Us[nb][w16][0]);  async16(up1 + (kk), &Us[nb][w16 + 8][0]); \
    async16(xp0 + (kk), &Xs[nb][w32][0]);  async16(xp1 + (kk), &Xs[nb][w32 + 8][0]); \
    async16(xp2 + (kk), &Xs[nb][w32 + 16][0]); async16(xp3 + (kk), &Xs[nb][w32 + 24][0]); }

    floatx4 aG[4][2], aU[4][2];
#pragma unroll
    for (int mi = 0; mi < 4; mi++)
#pragma unroll
        for (int nj = 0; nj < 2; nj++) {
            aG[mi][nj] = (floatx4){0.f, 0.f, 0.f, 0.f};
            aU[mi][nj] = (floatx4){0.f, 0.f, 0.f, 0.f};
        }

    // prologue
    STAGE(0, 0);
    asm volatile("s_waitcnt vmcnt(0)" ::: "memory");
    __builtin_amdgcn_s_barrier();

    const int NT = HDIM / 64;   // 16
#pragma unroll 1
    for (int t = 0; t < NT; ++t) {
        const int b = t & 1, nb = b ^ 1;
        if (t + 1 < NT) STAGE(nb, (t + 1) * 64);

        bf16x8 af[4][2], bg[2][2], bu[2][2];
#pragma unroll
        for (int mi = 0; mi < 4; mi++)
#pragma unroll
            for (int h = 0; h < 2; h++) {
                int row = wm * 64 + mi * 16 + l16;
                af[mi][h] = *(const bf16x8*)&Xs[b][row][(((h << 2) + quad) ^ sl) << 3];
            }
#pragma unroll
        for (int nj = 0; nj < 2; nj++)
#pragma unroll
            for (int h = 0; h < 2; h++) {
                int row = wn * 32 + nj * 16 + l16;
                int so = (((h << 2) + quad) ^ sl) << 3;
                bg[nj][h] = *(const bf16x8*)&Gs[b][row][so];
                bu[nj][h] = *(const bf16x8*)&Us[b][row][so];
            }
        asm volatile("s_waitcnt lgkmcnt(0)" ::: "memory");
        __builtin_amdgcn_sched_barrier(0);
        __builtin_amdgcn_s_setprio(1);
#pragma unroll
        for (int h = 0; h < 2; h++)
#pragma unroll
            for (int mi = 0; mi < 4; mi++)
#pragma unroll
                for (int nj = 0; nj < 2; nj++) {
                    aG[mi][nj] = __builtin_amdgcn_mfma_f32_16x16x32_bf16(af[mi][h], bg[nj][h], aG[mi][nj], 0, 0, 0);
                    aU[mi][nj] = __builtin_amdgcn_mfma_f32_16x16x32_bf16(af[mi][h], bu[nj][h], aU[mi][nj], 0, 0, 0);
                }
        __builtin_amdgcn_s_setprio(0);
        asm volatile("s_waitcnt vmcnt(0)" ::: "memory");
        __builtin_amdgcn_s_barrier();
    }
#undef STAGE

    // epilogue: SwiGLU + store (IDIM = 43*64 exact, no n-guard)
#pragma unroll
    for (int mi = 0; mi < 4; mi++)
#pragma unroll
        for (int nj = 0; nj < 2; nj++)
#pragma unroll
            for (int r = 0; r < 4; r++) {
                int m = ab0 + m0 + wm * 64 + mi * 16 + quad * 4 + r;
                int n = n0 + wn * 32 + nj * 16 + l16;
                float g = aG[mi][nj][r], u = aU[mi][nj][r];
                float a = g / (1.f + expf(-g)) * u;
                Ab[(size_t)m * IDIM + n] = f2bf(a);
            }
}

// ---------------- double-buffered down GEMM, all 9 experts, atomic into zeroed Y -----
__global__ void __launch_bounds__(256, 3)
gemm_down_db(const unsigned short* __restrict__ Ab,
             const unsigned short* __restrict__ Wd,
             size_t wstride,
             const int* __restrict__ idxb,
             const float* __restrict__ wgtb,
             const int* __restrict__ pcnt,
             const int* __restrict__ abrow,
             float* __restrict__ Y,
             int zbase) {
    const int e = zbase + blockIdx.z;
    const int cnt = (e == 8) ? TCNT : pcnt[e];
    const int m0 = blockIdx.x * BM;
    if (m0 >= cnt) return;
    const int n0 = blockIdx.y * BN;
    const unsigned short* DT = Wd + (size_t)e * wstride;
    const int* idx = (e == 8) ? nullptr : idxb + e * TCNT;
    const float* wgt = (e == 8) ? nullptr : wgtb + e * TCNT;
    const int ab0 = abrow[e];

    __shared__ unsigned short As[2][BM][64];   // 32 KB
    __shared__ unsigned short Ws[2][BN][64];   // 16 KB
    __shared__ int toks[BM];
    __shared__ float tw[BM];

    const int tid = threadIdx.x;
    const int wave = tid >> 6, lane = tid & 63;
    const int quad = lane >> 4, l16 = lane & 15;
    const int sl = l16 & 7;
    const int wm = wave >> 1, wn = wave & 1;
    const int w16 = wave * 16, w32 = wave * 32;
    const int rr = lane >> 3, cc = lane & 7;
    const int sw = (cc ^ rr) << 3;

    if (tid < BM) {
        toks[tid] = idx ? idx[m0 + tid] : (m0 + tid);
        tw[tid] = wgt ? wgt[m0 + tid] : 1.0f;
    }
    __syncthreads();

    const unsigned short* ap0 = Ab + (size_t)(ab0 + m0 + w32 + rr) * IDIM + sw;
    const unsigned short* ap1 = Ab + (size_t)(ab0 + m0 + w32 + 8 + rr) * IDIM + sw;
    const unsigned short* ap2 = Ab + (size_t)(ab0 + m0 + w32 + 16 + rr) * IDIM + sw;
    const unsigned short* ap3 = Ab + (size_t)(ab0 + m0 + w32 + 24 + rr) * IDIM + sw;
    const unsigned short* dp0 = DT + (size_t)(n0 + w16 + rr) * IDIM + sw;
    const unsigned short* dp1 = DT + (size_t)(n0 + w16 + 8 + rr) * IDIM + sw;

#define STAGE(nb, kk) {                                                        \
    async16(dp0 + (kk), &Ws[nb][w16][0]);  async16(dp1 + (kk), &Ws[nb][w16 + 8][0]); \
    async16(ap0 + (kk), &As[nb][w32][0]);  async16(ap1 + (kk), &As[nb][w32 + 8][0]); \
    async16(ap2 + (kk), &As[nb][w32 + 16][0]); async16(ap3 + (kk), &As[nb][w32 + 24][0]); }

    floatx4 acc[4][2];
#pragma unroll
    for (int mi = 0; mi < 4; mi++)
#pragma unroll
        for (int nj = 0; nj < 2; nj++) acc[mi][nj] = (floatx4){0.f, 0.f, 0.f, 0.f};

    STAGE(0, 0);
    asm volatile("s_waitcnt vmcnt(0)" ::: "memory");
    __builtin_amdgcn_s_barrier();

    const int NT = IDIM / 64;   // 43
#pragma unroll 1
    for (int t = 0; t < NT; ++t) {
        const int b = t & 1, nb = b ^ 1;
        if (t + 1 < NT) STAGE(nb, (t + 1) * 64);

        bf16x8 af[4][2], bw[2][2];
#pragma unroll
        for (int mi = 0; mi < 4; mi++)
#pragma unroll
            for (int h = 0; h < 2; h++) {
                int row = wm * 64 + mi * 16 + l16;
                af[mi][h] = *(const bf16x8*)&As[b][row][(((h << 2) + quad) ^ sl) << 3];
            }
#pragma unroll
        for (int nj = 0; nj < 2; nj++)
#pragma unroll
            for (int h = 0; h < 2; h++) {
                int row = wn * 32 + nj * 16 + l16;
                bw[nj][h] = *(const bf16x8*)&Ws[b][row][(((h << 2) + quad) ^ sl) << 3];
            }
        asm volatile("s_waitcnt lgkmcnt(0)" ::: "memory");
        __builtin_amdgcn_sched_barrier(0);
        __builtin_amdgcn_s_setprio(1);
#pragma unroll
        for (int h = 0; h < 2; h++)
#pragma unroll
            for (int mi = 0; mi < 4; mi++)
#pragma unroll
                for (int nj = 0; nj < 2; nj++)
                    acc[mi][nj] = __builtin_amdgcn_mfma_f32_16x16x32_bf16(af[mi][h], bw[nj][h], acc[mi][nj], 0, 0, 0);
        __builtin_amdgcn_s_setprio(0);
        asm volatile("s_waitcnt vmcnt(0)" ::: "memory");
        __builtin_amdgcn_s_barrier();
    }
#undef STAGE

    // Y pre-zeroed: every expert (incl. shared) scatter-adds; pad rows weight 0
#pragma unroll
    for (int mi = 0; mi < 4; mi++)
#pragma unroll
        for (int r = 0; r < 4; r++) {
            int lm = wm * 64 + mi * 16 + quad * 4 + r;
            int t = toks[lm];
            float w = tw[lm];
#pragma unroll
            for (int nj = 0; nj < 2; nj++) {
                int n = n0 + wn * 32 + nj * 16 + l16;
                atomicAdd(&Y[(size_t)t * HDIM + n], w * acc[mi][nj][r]);
            }
        }
}

extern "C" void kernel_launch(void* const* d_in, const int* in_sizes, int n_in,
                              void* d_out, int out_size, void* d_ws, size_t ws_size,
                              hipStream_t stream) {
    const float* x      = (const float*)d_in[0];
    const float* gate_w = (const float*)d_in[1];
    const float* wg     = (const float*)d_in[2];
    const float* wu     = (const float*)d_in[3];
    const float* wd     = (const float*)d_in[4];
    const float* sg     = (const float*)d_in[5];
    const float* su     = (const float*)d_in[6];
    const float* sd     = (const float*)d_in[7];
    float* y = (float*)d_out;

    const size_t HI   = (size_t)HDIM * IDIM;
    const size_t XB_B = (size_t)TCNT * HDIM * 2;
    const size_t AB_B = (size_t)ABCAP * IDIM * 2;
    const size_t LISTS_B = (size_t)NEXP * TCNT * 8 + (size_t)4 * TCNT * 4 + 256;
    const size_t need_sep   = XB_B + 27 * HI * 2 + AB_B + LISTS_B;  // ~311 MB
    const size_t need_alias = XB_B + 18 * HI * 2 + AB_B + LISTS_B;  // ~260 MB

    if (ws_size >= need_alias) {
        int sep = (ws_size >= need_sep) ? 1 : 0;
        unsigned short* xb  = (unsigned short*)d_ws;
        unsigned short* WgA = xb + (size_t)TCNT * HDIM;   // [9][I][H]
        unsigned short* WuA = WgA + 9 * HI;               // [9][I][H]
        unsigned short* WdA = sep ? (WuA + 9 * HI) : WgA; // own buffer or alias
        unsigned short* Ab  = sep ? (WdA + 9 * HI) : (WuA + 9 * HI);
        int*   idxb  = (int*)(Ab + (size_t)ABCAP * IDIM);
        float* wgtb  = (float*)(idxb + NEXP * TCNT);
        int*   topi  = (int*)(wgtb + NEXP * TCNT);
        float* topw  = (float*)(topi + 2 * TCNT);
        int*   pcnt  = (int*)(topw + 2 * TCNT);
        int*   abrow = pcnt + 16;

        zero_y<<<TCNT * HDIM / (256 * 4), 256, 0, stream>>>(y);
        cast_x<<<TCNT * HDIM / (256 * 8), 256, 0, stream>>>(x, xb);
        gate_kernel<<<TCNT / 4, 256, 0, stream>>>(x, gate_w, topi, topw);
        compact_k<<<NEXP, 256, 0, stream>>>(topi, topw, pcnt, idxb, wgtb);
        offsets_k<<<1, 64, 0, stream>>>(pcnt, abrow, 1);

        trans_gu_all<<<dim3(IDIM / 32, HDIM / 32, 18), 256, 0, stream>>>(
            wg, sg, wu, su, WgA, WuA, 0, HI);
        if (sep) {
            trans_d_all<<<dim3(HDIM / 32, IDIM / 32, 9), 256, 0, stream>>>(wd, sd, WdA, 0, HI);
            gemm_gu_db<<<dim3(TCNT / BM, IDIM / BN, 9), 256, 0, stream>>>(
                xb, WgA, WuA, HI, idxb, pcnt, abrow, Ab, 0);
        } else {
            gemm_gu_db<<<dim3(TCNT / BM, IDIM / BN, 9), 256, 0, stream>>>(
                xb, WgA, WuA, HI, idxb, pcnt, abrow, Ab, 0);
            trans_d_all<<<dim3(HDIM / 32, IDIM / 32, 9), 256, 0, stream>>>(wd, sd, WdA, 0, HI);
        }
        gemm_down_db<<<dim3(TCNT / BM, HDIM / BN, 9), 256, 0, stream>>>(
            Ab, WdA, HI, idxb, wgtb, pcnt, abrow, y, 0);
    } else {
        // -------- fallback: sequential per-expert --------
        unsigned short* WgT = (unsigned short*)d_ws;
        unsigned short* WuT = WgT + HI;
        unsigned short* Ab  = WuT + HI;                   // [T][I]
        int*   idxb  = (int*)(Ab + (size_t)TCNT * IDIM);
        float* wgtb  = (float*)(idxb + NEXP * TCNT);
        int*   topi  = (int*)(wgtb + NEXP * TCNT);
        float* topw  = (float*)(topi + 2 * TCNT);
        int*   pcnt  = (int*)(topw + 2 * TCNT);
        int*   abrow = pcnt + 16;
        unsigned short* xb = (unsigned short*)(abrow + 16);
        unsigned short* WdT = WgT;

        zero_y<<<TCNT * HDIM / (256 * 4), 256, 0, stream>>>(y);
        cast_x<<<TCNT * HDIM / (256 * 8), 256, 0, stream>>>(x, xb);
        gate_kernel<<<TCNT / 4, 256, 0, stream>>>(x, gate_w, topi, topw);
        compact_k<<<NEXP, 256, 0, stream>>>(topi, topw, pcnt, idxb, wgtb);
        offsets_k<<<1, 64, 0, stream>>>(pcnt, abrow, 0);

        trans_gu_all<<<dim3(IDIM / 32, HDIM / 32, 2), 256, 0, stream>>>(
            wg, sg, wu, su, WgT, WuT, 16, 0);
        gemm_gu_db<<<dim3(TCNT / BM, IDIM / BN, 1), 256, 0, stream>>>(
            xb, WgT, WuT, 0, idxb, pcnt, abrow, Ab, 8);
        trans_d_all<<<dim3(HDIM / 32, IDIM / 32, 1), 256, 0, stream>>>(wd, sd, WdT, 8, 0);
        gemm_down_db<<<dim3(TCNT / BM, HDIM / BN, 1), 256, 0, stream>>>(
            Ab, WdT, 0, idxb, wgtb, pcnt, abrow, y, 8);

        for (int e = 0; e < NEXP; e++) {
            trans_gu_all<<<dim3(IDIM / 32, HDIM / 32, 2), 256, 0, stream>>>(
                wg, sg, wu, su, WgT, WuT, 2 * e, 0);
            gemm_gu_db<<<dim3(TCNT / BM, IDIM / BN, 1), 256, 0, stream>>>(
                xb, WgT, WuT, 0, idxb, pcnt, abrow, Ab, e);
            trans_d_all<<<dim3(HDIM / 32, IDIM / 32, 1), 256, 0, stream>>>(wd, sd, WdT, e, 0);
            gemm_down_db<<<dim3(TCNT / BM, HDIM / BN, 1), 256, 0, stream>>>(
                Ab, WdT, 0, idxb, wgtb, pcnt, abrow, y, e);
        }
    }
}

// Round 6
// 1367.186 us; speedup vs baseline: 1.3583x; 1.0151x over previous
//
#include <hip/hip_runtime.h>
#include <hip/hip_bf16.h>

#define TCNT 8192   // B*S tokens
#define HDIM 1024
#define IDIM 2752
#define NEXP 8

#define BM 128
#define BN 64
// BK = 32 (64B LDS rows, slot-XOR swizzle), SINGLE buffer -> max occupancy

#define ABCAP 25600  // 8192 shared + 16384 routed + 8*128 pad
#define WLMAX 200    // 64 shared blocks + <=136 routed blocks

typedef short bf16x8 __attribute__((ext_vector_type(8)));
typedef float floatx4 __attribute__((ext_vector_type(4)));
typedef unsigned short ushortx8 __attribute__((ext_vector_type(8)));

__device__ __forceinline__ unsigned short f2bf(float f) {
    union { float f; unsigned u; } v; v.f = f;
    unsigned u = v.u;
    unsigned r = u + 0x7FFFu + ((u >> 16) & 1u);   // RNE
    return (unsigned short)(r >> 16);
}

// async global->LDS, 16B per lane; LDS dest = wave-uniform base + lane*16
__device__ __forceinline__ void async16(const unsigned short* g, unsigned short* l) {
    __builtin_amdgcn_global_load_lds(
        (const __attribute__((address_space(1))) unsigned int*)g,
        (__attribute__((address_space(3))) unsigned int*)l, 16, 0, 0);
}

// ---------------- zero Y ----------------
__global__ void zero_y(float* __restrict__ y) {
    size_t i = ((size_t)blockIdx.x * 256 + threadIdx.x) * 4;
    *(float4*)&y[i] = make_float4(0.f, 0.f, 0.f, 0.f);
}

// ---------------- cast x fp32 -> bf16 (once) ----------------
__global__ void cast_x(const float* __restrict__ x, unsigned short* __restrict__ xb) {
    size_t i = (size_t)blockIdx.x * 256 + threadIdx.x;   // 8 elems per thread
    const float4* p = (const float4*)x + i * 2;
    float4 a = p[0], b = p[1];
    ushortx8 o;
    o[0] = f2bf(a.x); o[1] = f2bf(a.y); o[2] = f2bf(a.z); o[3] = f2bf(a.w);
    o[4] = f2bf(b.x); o[5] = f2bf(b.y); o[6] = f2bf(b.z); o[7] = f2bf(b.w);
    *(ushortx8*)(xb + i * 8) = o;
}

// ---------------- gate: softmax + top2, no global atomics ----------------
__global__ void gate_kernel(const float* __restrict__ x,
                            const float* __restrict__ gw,
                            int* __restrict__ topi,
                            float* __restrict__ topw) {
    int wave = threadIdx.x >> 6;
    int lane = threadIdx.x & 63;
    int t = blockIdx.x * 4 + wave;
    float acc[NEXP];
#pragma unroll
    for (int e = 0; e < NEXP; e++) acc[e] = 0.f;
    const float* xp = x + (size_t)t * HDIM;
#pragma unroll
    for (int it = 0; it < HDIM / 64; it++) {
        float xv = xp[lane + 64 * it];
#pragma unroll
        for (int e = 0; e < NEXP; e++)
            acc[e] += xv * gw[e * HDIM + lane + 64 * it];
    }
#pragma unroll
    for (int e = 0; e < NEXP; e++) {
#pragma unroll
        for (int off = 32; off > 0; off >>= 1)
            acc[e] += __shfl_xor(acc[e], off);
    }
    if (lane == 0) {
        float m = acc[0];
#pragma unroll
        for (int e = 1; e < NEXP; e++) m = fmaxf(m, acc[e]);
        float p[NEXP], Z = 0.f;
#pragma unroll
        for (int e = 0; e < NEXP; e++) { p[e] = expf(acc[e] - m); Z += p[e]; }
        int i0 = 0;
#pragma unroll
        for (int e = 1; e < NEXP; e++) if (acc[e] > acc[i0]) i0 = e;
        int i1 = (i0 == 0) ? 1 : 0;
#pragma unroll
        for (int e = 0; e < NEXP; e++) {
            if (e == i0 || e == i1) continue;
            if (acc[e] > acc[i1]) i1 = e;
        }
        float p0 = p[i0] / Z, p1 = p[i1] / Z;
        float s = p0 + p1 + 1e-20f;
        topi[t * 2 + 0] = i0;  topw[t * 2 + 0] = p0 / s;
        topi[t * 2 + 1] = i1;  topw[t * 2 + 1] = p1 / s;
    }
}

// ---------------- compaction: one block per expert, LDS-atomic positions ----------------
__global__ void compact_k(const int* __restrict__ topi, const float* __restrict__ topw,
                          int* __restrict__ pcnt,
                          int* __restrict__ idxb, float* __restrict__ wgtb) {
    int e = blockIdx.x;
    __shared__ int base;
    if (threadIdx.x == 0) base = 0;
    __syncthreads();
    for (int i = threadIdx.x; i < 2 * TCNT; i += 256) {
        if (topi[i] == e) {
            int p = atomicAdd(&base, 1);
            idxb[e * TCNT + p] = i >> 1;
            wgtb[e * TCNT + p] = topw[i];
        }
    }
    __syncthreads();
    int c = base;
    int pc = (c + BM - 1) & ~(BM - 1);
    for (int i = c + threadIdx.x; i < pc; i += 256) {
        idxb[e * TCNT + i] = 0;
        wgtb[e * TCNT + i] = 0.f;
    }
    if (threadIdx.x == 0) pcnt[e] = pc;
}

// ---------------- Ab row offsets + GEMM worklist (e, m0 pairs) ----------------
__global__ void offsets_k(const int* __restrict__ pcnt, int* __restrict__ abrow,
                          int* __restrict__ wl, int* __restrict__ nblk, int fused) {
    if (threadIdx.x == 0) {
        int i = 0;
        for (int k = 0; k < TCNT / BM; k++) { wl[2 * i] = 8; wl[2 * i + 1] = k * BM; i++; }
        int off = TCNT;
        for (int e = 0; e < NEXP; e++) {
            abrow[e] = fused ? off : 0;
            int nb = pcnt[e] / BM;
            for (int k = 0; k < nb && i < WLMAX; k++) {
                wl[2 * i] = e; wl[2 * i + 1] = k * BM; i++;
            }
            off += pcnt[e];
        }
        abrow[8] = 0;
        *nblk = i;
    }
}

// ---------------- transpose+cast G/U: [H,I] fp32 -> [I,H] bf16 ----------------
__global__ void trans_gu_all(const float* __restrict__ wg, const float* __restrict__ sg,
                             const float* __restrict__ wu, const float* __restrict__ su,
                             unsigned short* __restrict__ outg, unsigned short* __restrict__ outu,
                             int zbase, size_t ostride) {
    const size_t HI = (size_t)HDIM * IDIM;
    int z = zbase + blockIdx.z;
    int e = z >> 1, which = z & 1;
    const float* in = which ? (e < 8 ? wu + (size_t)e * HI : su)
                            : (e < 8 ? wg + (size_t)e * HI : sg);
    unsigned short* out = (which ? outu : outg) + (size_t)e * ostride;
    const int R = HDIM, C = IDIM;
    __shared__ float tile[32][33];
    int r0 = blockIdx.y * 32, c0 = blockIdx.x * 32;
    int ty = threadIdx.x >> 3, tx = (threadIdx.x & 7) * 4;
    float4 v = *(const float4*)&in[(size_t)(r0 + ty) * C + c0 + tx];
    tile[ty][tx + 0] = v.x; tile[ty][tx + 1] = v.y;
    tile[ty][tx + 2] = v.z; tile[ty][tx + 3] = v.w;
    __syncthreads();
    int cy = ty, rx = tx;
    ushort4 o;
    o.x = f2bf(tile[rx + 0][cy]); o.y = f2bf(tile[rx + 1][cy]);
    o.z = f2bf(tile[rx + 2][cy]); o.w = f2bf(tile[rx + 3][cy]);
    *(ushort4*)&out[(size_t)(c0 + cy) * R + r0 + rx] = o;
}

// ---------------- transpose+cast D: [I,H] fp32 -> [H,I] bf16 ----------------
__global__ void trans_d_all(const float* __restrict__ wd, const float* __restrict__ sd,
                            unsigned short* __restrict__ outd, int zbase, size_t ostride) {
    const size_t HI = (size_t)HDIM * IDIM;
    int e = zbase + blockIdx.z;
    const float* in = (e < 8) ? wd + (size_t)e * HI : sd;
    unsigned short* out = outd + (size_t)e * ostride;
    const int R = IDIM, C = HDIM;
    __shared__ float tile[32][33];
    int r0 = blockIdx.y * 32, c0 = blockIdx.x * 32;
    int ty = threadIdx.x >> 3, tx = (threadIdx.x & 7) * 4;
    float4 v = *(const float4*)&in[(size_t)(r0 + ty) * C + c0 + tx];
    tile[ty][tx + 0] = v.x; tile[ty][tx + 1] = v.y;
    tile[ty][tx + 2] = v.z; tile[ty][tx + 3] = v.w;
    __syncthreads();
    int cy = ty, rx = tx;
    ushort4 o;
    o.x = f2bf(tile[rx + 0][cy]); o.y = f2bf(tile[rx + 1][cy]);
    o.z = f2bf(tile[rx + 2][cy]); o.w = f2bf(tile[rx + 3][cy]);
    *(ushort4*)&out[(size_t)(c0 + cy) * R + r0 + rx] = o;
}

// ---------------- fused G/U GEMM + SwiGLU: BK=32, single-buffer, 2-barrier ----------
// Occupancy-first: 16.8 KB LDS. Swizzle: LDS[row][slot] holds global chunk slot^(row&3).
__global__ void __launch_bounds__(256)
gemm_gu_s32(const unsigned short* __restrict__ xb,
            const unsigned short* __restrict__ Wg,
            const unsigned short* __restrict__ Wu,
            size_t wstride,
            const int* __restrict__ idxb,
            const int* __restrict__ pcnt,
            const int* __restrict__ abrow,
            const int* __restrict__ wl,     // worklist (e,m0) or null
            const int* __restrict__ nblk,
            unsigned short* __restrict__ Ab,
            int zbase) {
    int e, m0;
    if (wl) {
        int bx = blockIdx.x;
        if (bx >= *nblk) return;
        e = wl[2 * bx]; m0 = wl[2 * bx + 1];
    } else {
        e = zbase + blockIdx.z;
        m0 = blockIdx.x * BM;
        int cnt = (e == 8) ? TCNT : pcnt[e];
        if (m0 >= cnt) return;
    }
    const int n0 = blockIdx.y * BN;
    const unsigned short* GT = Wg + (size_t)e * wstride;
    const unsigned short* UT = Wu + (size_t)e * wstride;
    const int* idx = (e == 8) ? nullptr : idxb + e * TCNT;
    const int ab0 = abrow[e];

    __shared__ unsigned short Xs[BM][32];   // 8 KB
    __shared__ unsigned short Gs[BN][32];   // 4 KB
    __shared__ unsigned short Us[BN][32];   // 4 KB
    __shared__ int toks[BM];

    const int tid = threadIdx.x;
    const int wave = tid >> 6, lane = tid & 63;
    const int quad = lane >> 4, l16 = lane & 15;
    const int wm = wave >> 1, wn = wave & 1;   // wave tile: 64 m x 32 n
    const int w16 = wave * 16, w32 = wave * 32;
    const int r4 = lane >> 2;                  // 0..15: row within 16-row stage group
    const int sw32 = (((lane & 3) ^ (r4 & 3)) << 3);  // inverse-swizzled src slot (elems)

    if (tid < BM) toks[tid] = idx ? idx[m0 + tid] : (m0 + tid);
    __syncthreads();

    const unsigned short* xp0 = xb + (size_t)toks[w32 + r4] * HDIM + sw32;
    const unsigned short* xp1 = xb + (size_t)toks[w32 + 16 + r4] * HDIM + sw32;
    const unsigned short* gp  = GT + (size_t)(n0 + w16 + r4) * HDIM + sw32;
    const unsigned short* up  = UT + (size_t)(n0 + w16 + r4) * HDIM + sw32;

    floatx4 aG[4][2], aU[4][2];
#pragma unroll
    for (int mi = 0; mi < 4; mi++)
#pragma unroll
        for (int nj = 0; nj < 2; nj++) {
            aG[mi][nj] = (floatx4){0.f, 0.f, 0.f, 0.f};
            aU[mi][nj] = (floatx4){0.f, 0.f, 0.f, 0.f};
        }

    const int rsl = (quad ^ (l16 & 3)) << 3;   // read slot (elems): same for A and B rows

#pragma unroll 1
    for (int kb = 0; kb < HDIM; kb += 32) {
        async16(gp  + kb, &Gs[w16][0]);
        async16(up  + kb, &Us[w16][0]);
        async16(xp0 + kb, &Xs[w32][0]);
        async16(xp1 + kb, &Xs[w32 + 16][0]);
        __syncthreads();

        bf16x8 af[4], bg[2], bu[2];
#pragma unroll
        for (int mi = 0; mi < 4; mi++)
            af[mi] = *(const bf16x8*)&Xs[wm * 64 + mi * 16 + l16][rsl];
#pragma unroll
        for (int nj = 0; nj < 2; nj++) {
            bg[nj] = *(const bf16x8*)&Gs[wn * 32 + nj * 16 + l16][rsl];
            bu[nj] = *(const bf16x8*)&Us[wn * 32 + nj * 16 + l16][rsl];
        }
#pragma unroll
        for (int mi = 0; mi < 4; mi++)
#pragma unroll
            for (int nj = 0; nj < 2; nj++) {
                aG[mi][nj] = __builtin_amdgcn_mfma_f32_16x16x32_bf16(af[mi], bg[nj], aG[mi][nj], 0, 0, 0);
                aU[mi][nj] = __builtin_amdgcn_mfma_f32_16x16x32_bf16(af[mi], bu[nj], aU[mi][nj], 0, 0, 0);
            }
        __syncthreads();
    }

    // epilogue: SwiGLU + store (IDIM = 43*64 exact)
#pragma unroll
    for (int mi = 0; mi < 4; mi++)
#pragma unroll
        for (int nj = 0; nj < 2; nj++)
#pragma unroll
            for (int r = 0; r < 4; r++) {
                int m = ab0 + m0 + wm * 64 + mi * 16 + quad * 4 + r;
                int n = n0 + wn * 32 + nj * 16 + l16;
                float g = aG[mi][nj][r], u = aU[mi][nj][r];
                float a = g / (1.f + expf(-g)) * u;
                Ab[(size_t)m * IDIM + n] = f2bf(a);
            }
}

// ---------------- down GEMM: BK=32, single-buffer, atomic into zeroed Y -------------
__global__ void __launch_bounds__(256)
gemm_down_s32(const unsigned short* __restrict__ Ab,
              const unsigned short* __restrict__ Wd,
              size_t wstride,
              const int* __restrict__ idxb,
              const float* __restrict__ wgtb,
              const int* __restrict__ pcnt,
              const int* __restrict__ abrow,
              const int* __restrict__ wl,
              const int* __restrict__ nblk,
              float* __restrict__ Y,
              int zbase) {
    int e, m0;
    if (wl) {
        int bx = blockIdx.x;
        if (bx >= *nblk) return;
        e = wl[2 * bx]; m0 = wl[2 * bx + 1];
    } else {
        e = zbase + blockIdx.z;
        m0 = blockIdx.x * BM;
        int cnt = (e == 8) ? TCNT : pcnt[e];
        if (m0 >= cnt) return;
    }
    const int n0 = blockIdx.y * BN;
    const unsigned short* DT = Wd + (size_t)e * wstride;
    const int* idx = (e == 8) ? nullptr : idxb + e * TCNT;
    const float* wgt = (e == 8) ? nullptr : wgtb + e * TCNT;
    const int ab0 = abrow[e];

    __shared__ unsigned short As[BM][32];   // 8 KB
    __shared__ unsigned short Ws[BN][32];   // 4 KB
    __shared__ int toks[BM];
    __shared__ float tw[BM];

    const int tid = threadIdx.x;
    const int wave = tid >> 6, lane = tid & 63;
    const int quad = lane >> 4, l16 = lane & 15;
    const int wm = wave >> 1, wn = wave & 1;
    const int w16 = wave * 16, w32 = wave * 32;
    const int r4 = lane >> 2;
    const int sw32 = (((lane & 3) ^ (r4 & 3)) << 3);

    if (tid < BM) {
        toks[tid] = idx ? idx[m0 + tid] : (m0 + tid);
        tw[tid] = wgt ? wgt[m0 + tid] : 1.0f;
    }
    __syncthreads();

    const unsigned short* ap0 = Ab + (size_t)(ab0 + m0 + w32 + r4) * IDIM + sw32;
    const unsigned short* ap1 = Ab + (size_t)(ab0 + m0 + w32 + 16 + r4) * IDIM + sw32;
    const unsigned short* dp  = DT + (size_t)(n0 + w16 + r4) * IDIM + sw32;

    floatx4 acc[4][2];
#pragma unroll
    for (int mi = 0; mi < 4; mi++)
#pragma unroll
        for (int nj = 0; nj < 2; nj++) acc[mi][nj] = (floatx4){0.f, 0.f, 0.f, 0.f};

    const int rsl = (quad ^ (l16 & 3)) << 3;

#pragma unroll 1
    for (int kb = 0; kb < IDIM; kb += 32) {
        async16(dp  + kb, &Ws[w16][0]);
        async16(ap0 + kb, &As[w32][0]);
        async16(ap1 + kb, &As[w32 + 16][0]);
        __syncthreads();

        bf16x8 af[4], bw[2];
#pragma unroll
        for (int mi = 0; mi < 4; mi++)
            af[mi] = *(const bf16x8*)&As[wm * 64 + mi * 16 + l16][rsl];
#pragma unroll
        for (int nj = 0; nj < 2; nj++)
            bw[nj] = *(const bf16x8*)&Ws[wn * 32 + nj * 16 + l16][rsl];
#pragma unroll
        for (int mi = 0; mi < 4; mi++)
#pragma unroll
            for (int nj = 0; nj < 2; nj++)
                acc[mi][nj] = __builtin_amdgcn_mfma_f32_16x16x32_bf16(af[mi], bw[nj], acc[mi][nj], 0, 0, 0);
        __syncthreads();
    }

    // Y pre-zeroed: every expert (incl. shared) scatter-adds; pad rows weight 0
#pragma unroll
    for (int mi = 0; mi < 4; mi++)
#pragma unroll
        for (int r = 0; r < 4; r++) {
            int lm = wm * 64 + mi * 16 + quad * 4 + r;
            int t = toks[lm];
            float w = tw[lm];
#pragma unroll
            for (int nj = 0; nj < 2; nj++) {
                int n = n0 + wn * 32 + nj * 16 + l16;
                atomicAdd(&Y[(size_t)t * HDIM + n], w * acc[mi][nj][r]);
            }
        }
}

extern "C" void kernel_launch(void* const* d_in, const int* in_sizes, int n_in,
                              void* d_out, int out_size, void* d_ws, size_t ws_size,
                              hipStream_t stream) {
    const float* x      = (const float*)d_in[0];
    const float* gate_w = (const float*)d_in[1];
    const float* wg     = (const float*)d_in[2];
    const float* wu     = (const float*)d_in[3];
    const float* wd     = (const float*)d_in[4];
    const float* sg     = (const float*)d_in[5];
    const float* su     = (const float*)d_in[6];
    const float* sd     = (const float*)d_in[7];
    float* y = (float*)d_out;

    const size_t HI   = (size_t)HDIM * IDIM;
    const size_t XB_B = (size_t)TCNT * HDIM * 2;
    const size_t AB_B = (size_t)ABCAP * IDIM * 2;
    const size_t LISTS_B = (size_t)NEXP * TCNT * 8 + (size_t)4 * TCNT * 4 + 4096;
    const size_t need_sep   = XB_B + 27 * HI * 2 + AB_B + LISTS_B;  // ~311 MB
    const size_t need_alias = XB_B + 18 * HI * 2 + AB_B + LISTS_B;  // ~260 MB

    if (ws_size >= need_alias) {
        int sep = (ws_size >= need_sep) ? 1 : 0;
        unsigned short* xb  = (unsigned short*)d_ws;
        unsigned short* WgA = xb + (size_t)TCNT * HDIM;   // [9][I][H]
        unsigned short* WuA = WgA + 9 * HI;               // [9][I][H]
        unsigned short* WdA = sep ? (WuA + 9 * HI) : WgA; // own buffer or alias
        unsigned short* Ab  = sep ? (WdA + 9 * HI) : (WuA + 9 * HI);
        int*   idxb  = (int*)(Ab + (size_t)ABCAP * IDIM);
        float* wgtb  = (float*)(idxb + NEXP * TCNT);
        int*   topi  = (int*)(wgtb + NEXP * TCNT);
        float* topw  = (float*)(topi + 2 * TCNT);
        int*   pcnt  = (int*)(topw + 2 * TCNT);
        int*   abrow = pcnt + 16;
        int*   nblk  = abrow + 16;
        int*   wl    = nblk + 16;                          // [2*WLMAX]

        zero_y<<<TCNT * HDIM / (256 * 4), 256, 0, stream>>>(y);
        cast_x<<<TCNT * HDIM / (256 * 8), 256, 0, stream>>>(x, xb);
        gate_kernel<<<TCNT / 4, 256, 0, stream>>>(x, gate_w, topi, topw);
        compact_k<<<NEXP, 256, 0, stream>>>(topi, topw, pcnt, idxb, wgtb);
        offsets_k<<<1, 64, 0, stream>>>(pcnt, abrow, wl, nblk, 1);

        trans_gu_all<<<dim3(IDIM / 32, HDIM / 32, 18), 256, 0, stream>>>(
            wg, sg, wu, su, WgA, WuA, 0, HI);
        if (sep) {
            trans_d_all<<<dim3(HDIM / 32, IDIM / 32, 9), 256, 0, stream>>>(wd, sd, WdA, 0, HI);
            gemm_gu_s32<<<dim3(WLMAX, IDIM / BN, 1), 256, 0, stream>>>(
                xb, WgA, WuA, HI, idxb, pcnt, abrow, wl, nblk, Ab, 0);
        } else {
            gemm_gu_s32<<<dim3(WLMAX, IDIM / BN, 1), 256, 0, stream>>>(
                xb, WgA, WuA, HI, idxb, pcnt, abrow, wl, nblk, Ab, 0);
            trans_d_all<<<dim3(HDIM / 32, IDIM / 32, 9), 256, 0, stream>>>(wd, sd, WdA, 0, HI);
        }
        gemm_down_s32<<<dim3(WLMAX, HDIM / BN, 1), 256, 0, stream>>>(
            Ab, WdA, HI, idxb, wgtb, pcnt, abrow, wl, nblk, y, 0);
    } else {
        // -------- fallback: sequential per-expert --------
        unsigned short* WgT = (unsigned short*)d_ws;
        unsigned short* WuT = WgT + HI;
        unsigned short* Ab  = WuT + HI;                   // [T][I]
        int*   idxb  = (int*)(Ab + (size_t)TCNT * IDIM);
        float* wgtb  = (float*)(idxb + NEXP * TCNT);
        int*   topi  = (int*)(wgtb + NEXP * TCNT);
        float* topw  = (float*)(topi + 2 * TCNT);
        int*   pcnt  = (int*)(topw + 2 * TCNT);
        int*   abrow = pcnt + 16;
        int*   nblk  = abrow + 16;
        int*   wl    = nblk + 16;
        unsigned short* xb = (unsigned short*)(wl + 2 * WLMAX);
        unsigned short* WdT = WgT;

        zero_y<<<TCNT * HDIM / (256 * 4), 256, 0, stream>>>(y);
        cast_x<<<TCNT * HDIM / (256 * 8), 256, 0, stream>>>(x, xb);
        gate_kernel<<<TCNT / 4, 256, 0, stream>>>(x, gate_w, topi, topw);
        compact_k<<<NEXP, 256, 0, stream>>>(topi, topw, pcnt, idxb, wgtb);
        offsets_k<<<1, 64, 0, stream>>>(pcnt, abrow, wl, nblk, 0);

        trans_gu_all<<<dim3(IDIM / 32, HDIM / 32, 2), 256, 0, stream>>>(
            wg, sg, wu, su, WgT, WuT, 16, 0);
        gemm_gu_s32<<<dim3(TCNT / BM, IDIM / BN, 1), 256, 0, stream>>>(
            xb, WgT, WuT, 0, idxb, pcnt, abrow, nullptr, nullptr, Ab, 8);
        trans_d_all<<<dim3(HDIM / 32, IDIM / 32, 1), 256, 0, stream>>>(wd, sd, WdT, 8, 0);
        gemm_down_s32<<<dim3(TCNT / BM, HDIM / BN, 1), 256, 0, stream>>>(
            Ab, WdT, 0, idxb, wgtb, pcnt, abrow, nullptr, nullptr, y, 8);

        for (int e = 0; e < NEXP; e++) {
            trans_gu_all<<<dim3(IDIM / 32, HDIM / 32, 2), 256, 0, stream>>>(
                wg, sg, wu, su, WgT, WuT, 2 * e, 0);
            gemm_gu_s32<<<dim3(TCNT / BM, IDIM / BN, 1), 256, 0, stream>>>(
                xb, WgT, WuT, 0, idxb, pcnt, abrow, nullptr, nullptr, Ab, e);
            trans_d_all<<<dim3(HDIM / 32, IDIM / 32, 1), 256, 0, stream>>>(wd, sd, WdT, e, 0);
            gemm_down_s32<<<dim3(TCNT / BM, HDIM / BN, 1), 256, 0, stream>>>(
                Ab, WdT, 0, idxb, wgtb, pcnt, abrow, nullptr, nullptr, y, e);
        }
    }
}